// Round 4
// baseline (501.647 us; speedup 1.0000x reference)
//
#include <hip/hip_runtime.h>

// StackLSTMCell: B=256, IN=256, H=256, L=2, S=128 (SLOTS=129). All f32.
//
// Single persistent-grid kernel (plus a 64-thread barrier-init kernel).
// Phases, separated by manual device-scope grid barriers:
//   P1: blocks[0,64) gemm0 (32x128 tile, 4x4 reg tile, K=512)
//       blocks[64,G) copy combined-stack span [0, S1T)
//   P2: blocks[0,64) act0 (4 elems/thread); others copy [S1T, S2T)
//   P3: blocks[0,64) gemm1; others copy [S2T, CTOT)
//   P4: blocks[0,256) overwrite pos+1 slot in both out-stacks; block 0 also
//       finalizes h_out/c_out.
// Co-residency is guaranteed by G = hipOccupancyMaxActiveBlocksPerMultiprocessor
// * 256 (capped at 1024) with __launch_bounds__(256,4). Barrier state lives in
// d_ws and is zeroed by init_k every execution (replay/poison-safe). The spin
// has a bailout valve so any residency bug degrades to wrong-answer, not hang.

#define NV4   4227072             // float4 per stack (129*256*256*2/4)
#define CTOT  8454144             // float4 both stacks
#define S1T   2818048             // copy thirds
#define S2T   5636096
#define STACK_ELEMS 16908288      // floats per stack

static __device__ __forceinline__ float sigf(float x) {
    return 1.0f / (1.0f + __expf(-x));
}
static __device__ __forceinline__ float tanh_fast(float x) {
    return 2.0f / (1.0f + __expf(-2.0f * x)) - 1.0f;
}

// ---------------------------------------------------------------------------
// device-scope grid barrier; slot state = {arrive, release} ints, zero-init.
static __device__ __forceinline__ void gbar(int* bar, int slot, int nb)
{
    __syncthreads();
    if (threadIdx.x == 0) {
        __threadfence();                        // release: wb own L1/L2
        int* arr = bar + slot * 2;
        if (atomicAdd(arr, 1) == nb - 1) {
            __hip_atomic_store(arr + 1, 1, __ATOMIC_RELEASE,
                               __HIP_MEMORY_SCOPE_AGENT);
        } else {
            int spins = 0;
            while (!__hip_atomic_load(arr + 1, __ATOMIC_ACQUIRE,
                                      __HIP_MEMORY_SCOPE_AGENT)) {
                __builtin_amdgcn_s_sleep(2);
                if (++spins > (1 << 22)) break; // valve: never hang
            }
        }
        __threadfence();                        // acquire: inv own L1/L2
    }
    __syncthreads();
}

// ---------------------------------------------------------------------------
// combined-stack passthrough copy, grid-stride over copier blocks, 4x unroll
static __device__ __forceinline__ void do_copy(
    const float4* __restrict__ hin, float4* __restrict__ hout,
    const float4* __restrict__ cin, float4* __restrict__ cout,
    int lo, int hi, int cb, int ncb)
{
    int stride = ncb << 8;
    int i = lo + (cb << 8) + (int)threadIdx.x;
    int lim3 = hi - 3 * stride;                 // i < lim3 <=> i+3*stride < hi
    for (; i < lim3; i += stride << 2) {
        int i1 = i + stride, i2 = i + 2 * stride, i3 = i + 3 * stride;
        const float4* p0 = (i  < NV4) ? hin + i  : cin + (i  - NV4);
        const float4* p1 = (i1 < NV4) ? hin + i1 : cin + (i1 - NV4);
        const float4* p2 = (i2 < NV4) ? hin + i2 : cin + (i2 - NV4);
        const float4* p3 = (i3 < NV4) ? hin + i3 : cin + (i3 - NV4);
        float4 v0 = *p0, v1 = *p1, v2 = *p2, v3 = *p3;
        float4* q0 = (i  < NV4) ? hout + i  : cout + (i  - NV4);
        float4* q1 = (i1 < NV4) ? hout + i1 : cout + (i1 - NV4);
        float4* q2 = (i2 < NV4) ? hout + i2 : cout + (i2 - NV4);
        float4* q3 = (i3 < NV4) ? hout + i3 : cout + (i3 - NV4);
        *q0 = v0; *q1 = v1; *q2 = v2; *q3 = v3;
    }
    for (; i < hi; i += stride) {
        const float4* p = (i < NV4) ? hin + i : cin + (i - NV4);
        float4 v = *p;
        float4* q = (i < NV4) ? hout + i : cout + (i - NV4);
        *q = v;
    }
}

// ---------------------------------------------------------------------------
// GEMM block (blockIdx.x in [0,64)): gates = A(256x512) @ [wih|whh]^T + biases
// A row b: k<256 -> a_lo[b*256+k]; k>=256 -> a_hi stride-2 gather at pos[b].
// Tile 32x128, thread-tile 4x4, K-subtiles of 32 with register prefetch.
static __device__ __forceinline__ void gemm_block(
    const float* __restrict__ a_lo, const float* __restrict__ a_hi,
    const int* __restrict__ pos,
    const float* __restrict__ wih, const float* __restrict__ whh,
    const float* __restrict__ bih, const float* __restrict__ bhh,
    float* __restrict__ gates)
{
    __shared__ float As[32][36];       // [k][b]
    __shared__ float Ws[32][132];      // [k][j]
    int t   = threadIdx.x;
    int tb  = blockIdx.x;              // 0..63
    int bm0 = (tb >> 3) << 5;
    int jt0 = (tb & 7) << 7;
    int arow = t >> 3, ak4 = (t & 7) << 2;
    int ab = bm0 + arow, ap = pos[ab];
    int wrow = t >> 1, wk = (t & 1) << 4;
    int wj = jt0 + wrow;
    int tx = t & 31, ty = t >> 5;

    float4 apre, wpre0, wpre1, wpre2, wpre3;
    // prefetch subtile 0 (k in [0,32): always a_lo / wih)
    apre = *(const float4*)&a_lo[ab * 256 + ak4];
    {
        const float* ws = &wih[wj * 256 + wk];
        wpre0 = *(const float4*)(ws + 0);
        wpre1 = *(const float4*)(ws + 4);
        wpre2 = *(const float4*)(ws + 8);
        wpre3 = *(const float4*)(ws + 12);
    }
    float acc[4][4] = {{0.f, 0.f, 0.f, 0.f}};
    for (int s = 0; s < 16; ++s) {
        __syncthreads();
        As[ak4 + 0][arow] = apre.x;
        As[ak4 + 1][arow] = apre.y;
        As[ak4 + 2][arow] = apre.z;
        As[ak4 + 3][arow] = apre.w;
        Ws[wk + 0][wrow]  = wpre0.x;  Ws[wk + 1][wrow]  = wpre0.y;
        Ws[wk + 2][wrow]  = wpre0.z;  Ws[wk + 3][wrow]  = wpre0.w;
        Ws[wk + 4][wrow]  = wpre1.x;  Ws[wk + 5][wrow]  = wpre1.y;
        Ws[wk + 6][wrow]  = wpre1.z;  Ws[wk + 7][wrow]  = wpre1.w;
        Ws[wk + 8][wrow]  = wpre2.x;  Ws[wk + 9][wrow]  = wpre2.y;
        Ws[wk + 10][wrow] = wpre2.z;  Ws[wk + 11][wrow] = wpre2.w;
        Ws[wk + 12][wrow] = wpre3.x;  Ws[wk + 13][wrow] = wpre3.y;
        Ws[wk + 14][wrow] = wpre3.z;  Ws[wk + 15][wrow] = wpre3.w;
        if (s < 15) {                  // prefetch subtile s+1
            int kg = ((s + 1) << 5) + ak4;
            if (kg < 256) {
                apre = *(const float4*)&a_lo[ab * 256 + kg];
            } else {
                const float* ah = a_hi + ((ap * 256 + ab) * 256 + (kg - 256)) * 2;
                apre.x = ah[0]; apre.y = ah[2]; apre.z = ah[4]; apre.w = ah[6];
            }
            int kk = ((s + 1) << 5) + wk;
            const float* ws = (kk < 256) ? &wih[wj * 256 + kk]
                                         : &whh[wj * 256 + kk - 256];
            wpre0 = *(const float4*)(ws + 0);
            wpre1 = *(const float4*)(ws + 4);
            wpre2 = *(const float4*)(ws + 8);
            wpre3 = *(const float4*)(ws + 12);
        }
        __syncthreads();
        #pragma unroll
        for (int k = 0; k < 32; ++k) {
            float4 av = *(const float4*)&As[k][ty << 2];
            float4 wv = *(const float4*)&Ws[k][tx << 2];
            acc[0][0] = fmaf(av.x, wv.x, acc[0][0]);
            acc[0][1] = fmaf(av.x, wv.y, acc[0][1]);
            acc[0][2] = fmaf(av.x, wv.z, acc[0][2]);
            acc[0][3] = fmaf(av.x, wv.w, acc[0][3]);
            acc[1][0] = fmaf(av.y, wv.x, acc[1][0]);
            acc[1][1] = fmaf(av.y, wv.y, acc[1][1]);
            acc[1][2] = fmaf(av.y, wv.z, acc[1][2]);
            acc[1][3] = fmaf(av.y, wv.w, acc[1][3]);
            acc[2][0] = fmaf(av.z, wv.x, acc[2][0]);
            acc[2][1] = fmaf(av.z, wv.y, acc[2][1]);
            acc[2][2] = fmaf(av.z, wv.z, acc[2][2]);
            acc[2][3] = fmaf(av.z, wv.w, acc[2][3]);
            acc[3][0] = fmaf(av.w, wv.x, acc[3][0]);
            acc[3][1] = fmaf(av.w, wv.y, acc[3][1]);
            acc[3][2] = fmaf(av.w, wv.z, acc[3][2]);
            acc[3][3] = fmaf(av.w, wv.w, acc[3][3]);
        }
    }
    int j = jt0 + (tx << 2);
    float4 b0 = *(const float4*)&bih[j];
    float4 b1 = *(const float4*)&bhh[j];
    float* gp = gates + (bm0 + (ty << 2)) * 1024 + j;
    #pragma unroll
    for (int i = 0; i < 4; ++i) {
        float4 r;
        r.x = acc[i][0] + b0.x + b1.x;
        r.y = acc[i][1] + b0.y + b1.y;
        r.z = acc[i][2] + b0.z + b1.z;
        r.w = acc[i][3] + b0.w + b1.w;
        *(float4*)&gp[i * 1024] = r;
    }
}

// ---------------------------------------------------------------------------
static __device__ __forceinline__ void lstm1(
    const float* __restrict__ gates, const float* __restrict__ cel,
    int p, int b, int h, float& hv, float& cv)
{
    float cin = cel[((p * 256 + b) * 256 + h) * 2 + 1];    // l=1
    const float* g = gates + b * 1024 + h;
    float gi = g[0], gf = g[256], gg = g[512], go = g[768];
    cv = sigf(gf) * cin + sigf(gi) * tanh_fast(gg);
    hv = sigf(go) * tanh_fast(cv);
}

// ---------------------------------------------------------------------------
__global__ void init_k(int* bar) {
    if (threadIdx.x < 8) bar[threadIdx.x] = 0;
}

__global__ __launch_bounds__(256, 4) void fused_k(
    const float* __restrict__ x, const float* __restrict__ hid,
    const float* __restrict__ cel,
    const float* __restrict__ wih0, const float* __restrict__ whh0,
    const float* __restrict__ bih0, const float* __restrict__ bhh0,
    const float* __restrict__ wih1, const float* __restrict__ whh1,
    const float* __restrict__ bih1, const float* __restrict__ bhh1,
    const int* __restrict__ op, const int* __restrict__ pos,
    float* __restrict__ gates, float* __restrict__ h0f,
    float* __restrict__ c0f, float* __restrict__ out, int* bar)
{
    int bid = blockIdx.x, G = gridDim.x;
    const float4* hin = (const float4*)hid;
    const float4* cin = (const float4*)cel;
    float4* hout = (float4*)(out + 1024);
    float4* cout = (float4*)(out + 1024 + STACK_ELEMS);

    // ---- P1: gemm0 | copy [0, S1T)
    if (bid < 64) gemm_block(x, hid, pos, wih0, whh0, bih0, bhh0, gates);
    else          do_copy(hin, hout, cin, cout, 0, S1T, bid - 64, G - 64);
    gbar(bar, 0, G);

    // ---- P2: act0 | copy [S1T, S2T)
    if (bid < 64) {
        #pragma unroll
        for (int r = 0; r < 4; ++r) {
            int e = r * 16384 + bid * 256 + (int)threadIdx.x;
            int b = e >> 8, h = e & 255;
            float cv0 = cel[((pos[b] * 256 + b) * 256 + h) * 2];   // l=0
            const float* g = gates + b * 1024 + h;
            float gi = g[0], gf = g[256], gg = g[512], go = g[768];
            float c  = sigf(gf) * cv0 + sigf(gi) * tanh_fast(gg);
            h0f[e] = sigf(go) * tanh_fast(c);
            c0f[e] = c;
        }
    } else {
        do_copy(hin, hout, cin, cout, S1T, S2T, bid - 64, G - 64);
    }
    gbar(bar, 1, G);

    // ---- P3: gemm1 | copy [S2T, CTOT)
    if (bid < 64) gemm_block(h0f, hid + 1, pos, wih1, whh1, bih1, bhh1, gates);
    else          do_copy(hin, hout, cin, cout, S2T, CTOT, bid - 64, G - 64);
    gbar(bar, 2, G);

    // ---- P4: slot overwrite + finalize
    for (int v = bid * 256 + (int)threadIdx.x; v < 65536; v += G * 256) {
        bool is_cell = v >= 32768;
        int vv = v & 32767;
        int b = vv >> 7, q = vv & 127;
        int p = pos[b];
        int h = q * 2;
        float h1a, c1a, h1b, c1b;
        lstm1(gates, cel, p, b, h,     h1a, c1a);
        lstm1(gates, cel, p, b, h + 1, h1b, c1b);
        float4 val;
        if (is_cell) {
            val.x = c0f[b * 256 + h];     val.y = c1a;
            val.z = c0f[b * 256 + h + 1]; val.w = c1b;
        } else {
            val.x = h0f[b * 256 + h];     val.y = h1a;
            val.z = h0f[b * 256 + h + 1]; val.w = h1b;
        }
        float4* dst = is_cell ? cout : hout;
        dst[(p + 1) * 32768 + b * 128 + q] = val;
    }
    if (bid == 0) {
        int b = threadIdx.x;
        int o = op[b];
        int p = pos[b];
        float h0v, h1v, c0v, c1v;
        if (o == 1) {            // new_pos == pos+1: freshly computed slot
            h0v = h0f[b * 256 + 255];
            c0v = c0f[b * 256 + 255];
            lstm1(gates, cel, p, b, 255, h1v, c1v);
        } else {                 // untouched slot: passthrough from input
            int base2 = (((p + o) * 256 + b) * 256 + 255) * 2;
            h0v = hid[base2]; h1v = hid[base2 + 1];
            c0v = cel[base2]; c1v = cel[base2 + 1];
        }
        out[b * 2]           = h0v;
        out[b * 2 + 1]       = h1v;
        out[512 + b * 2]     = c0v;
        out[512 + b * 2 + 1] = c1v;
    }
}

// ---------------------------------------------------------------------------
extern "C" void kernel_launch(void* const* d_in, const int* in_sizes, int n_in,
                              void* d_out, int out_size, void* d_ws, size_t ws_size,
                              hipStream_t stream) {
    const float* x    = (const float*)d_in[0];
    const float* hid  = (const float*)d_in[1];
    const float* cel  = (const float*)d_in[2];
    const float* wih0 = (const float*)d_in[3];
    const float* whh0 = (const float*)d_in[4];
    const float* bih0 = (const float*)d_in[5];
    const float* bhh0 = (const float*)d_in[6];
    const float* wih1 = (const float*)d_in[7];
    const float* whh1 = (const float*)d_in[8];
    const float* bih1 = (const float*)d_in[9];
    const float* bhh1 = (const float*)d_in[10];
    const int* op  = (const int*)d_in[11];
    const int* pos = (const int*)d_in[12];
    float* out = (float*)d_out;

    // workspace: gates 256x1024, h0f/c0f 256x256, then 8 barrier ints
    float* W     = (float*)d_ws;
    float* gates = W;
    float* h0f   = W + 262144;
    float* c0f   = W + 327680;
    int*   bar   = (int*)(W + 393216);

    static int G = 0;
    if (G == 0) {
        int maxb = 0;
        if (hipOccupancyMaxActiveBlocksPerMultiprocessor(&maxb, fused_k, 256, 0)
                != hipSuccess || maxb < 1)
            maxb = 1;
        G = maxb * 256;            // guaranteed co-resident
        if (G > 1024) G = 1024;    // BW saturates; keep barrier cheap
    }

    init_k<<<1, 64, 0, stream>>>(bar);
    fused_k<<<G, 256, 0, stream>>>(x, hid, cel, wih0, whh0, bih0, bhh0,
                                   wih1, whh1, bih1, bhh1, op, pos,
                                   gates, h0f, c0f, out, bar);
}